// Round 1
// baseline (2509.308 us; speedup 1.0000x reference)
//
#include <hip/hip_runtime.h>
#include <math.h>

// Problem constants (fixed by the reference)
#define N_B 8
#define H_B 8
#define D_B 64
#define L_B 16384
#define M_B 256
#define C_B 64
#define NH  64      // N*H
#define HC  512     // H*C

// Workspace layout (float offsets)
#define WS_SK   0          // [NH][64]  column sums of K
#define WS_GK   4096       // [NH][64][64] K gram
#define WS_LIN  266240     // [8]  sum of sim per h
#define WS_SSQ  266248     // [8]  sum of sim^2 per h
#define WS_A    266256     // [8]  softmax scale per h
#define WS_S1   266264     // [512] BN1d sum
#define WS_S2   266776     // [512] BN1d sumsq
#define WS_SC   267288     // [512] BN1d scale
#define WS_SH   267800     // [512] BN1d shift
#define WS_TOT  268312

// ---------------- k1a: K gram (GK) + K column sums (SK), per (n,h) ----------
__global__ __launch_bounds__(256) void k1a_gram_k(const float* __restrict__ key,
                                                  float* __restrict__ ws) {
    const int nh = blockIdx.x;
    const int tid = threadIdx.x;
    __shared__ float Ks[D_B][260];

    const float4* kp4 = (const float4*)(key + (size_t)nh * D_B * M_B);
#pragma unroll
    for (int i = 0; i < 16; ++i) {
        int idx4 = i * 256 + tid;          // 4096 float4 total
        int d = idx4 >> 6;                 // 64 float4 per row
        int mf = idx4 & 63;
        *(float4*)&Ks[d][mf * 4] = kp4[idx4];
    }
    __syncthreads();

    const int tr = tid >> 4, tc = tid & 15;
    float acc[4][4] = {};
#pragma unroll 4
    for (int m = 0; m < M_B; ++m) {
        float a4[4], b4[4];
#pragma unroll
        for (int i = 0; i < 4; ++i) a4[i] = Ks[tr * 4 + i][m];
#pragma unroll
        for (int j = 0; j < 4; ++j) b4[j] = Ks[tc * 4 + j][m];
#pragma unroll
        for (int i = 0; i < 4; ++i)
#pragma unroll
            for (int j = 0; j < 4; ++j) acc[i][j] += a4[i] * b4[j];
    }
    float* gk = ws + WS_GK + (size_t)nh * 4096;
#pragma unroll
    for (int i = 0; i < 4; ++i) {
        float4 o = {acc[i][0], acc[i][1], acc[i][2], acc[i][3]};
        *(float4*)&gk[(tr * 4 + i) * 64 + tc * 4] = o;
    }
    if (tid < 64) {
        float s = 0.f;
        for (int m = 0; m < M_B; ++m) s += Ks[tid][m];
        ws[WS_SK + nh * 64 + tid] = s;
    }
}

// ------------- k1b: BN2d stats via Gram contraction (one thread per l) ------
__global__ __launch_bounds__(256) void k1b_stats_q(const float* __restrict__ query,
                                                   float* __restrict__ ws) {
    const int nh = blockIdx.y;
    const int h = nh & 7;
    const int l = blockIdx.x * 256 + threadIdx.x;

    const float* qp = query + (size_t)nh * D_B * L_B + l;
    float q[64];
#pragma unroll
    for (int d = 0; d < 64; ++d) q[d] = qp[(size_t)d * L_B];

    // sum over m of sim[l,m] = dot(q_l, colsumK)
    const float* sk = ws + WS_SK + nh * 64;
    float lin = 0.f;
#pragma unroll
    for (int d = 0; d < 64; ++d) lin += q[d] * sk[d];

    // sum over m of sim[l,m]^2 = q_l^T GK q_l
    const float* gk = ws + WS_GK + (size_t)nh * 4096;
    float ssq = 0.f;
#pragma unroll
    for (int i = 0; i < 64; ++i) {
        float t0 = 0.f, t1 = 0.f, t2 = 0.f, t3 = 0.f;
#pragma unroll
        for (int j = 0; j < 16; ++j) {
            const float4 g = *(const float4*)&gk[i * 64 + j * 4];
            t0 += g.x * q[j * 4 + 0];
            t1 += g.y * q[j * 4 + 1];
            t2 += g.z * q[j * 4 + 2];
            t3 += g.w * q[j * 4 + 3];
        }
        ssq += ((t0 + t1) + (t2 + t3)) * q[i];
    }

#pragma unroll
    for (int off = 1; off < 64; off <<= 1) {
        lin += __shfl_xor(lin, off);
        ssq += __shfl_xor(ssq, off);
    }
    if ((threadIdx.x & 63) == 0) {
        atomicAdd(ws + WS_LIN + h, lin);
        atomicAdd(ws + WS_SSQ + h, ssq);
    }
}

// ---------------- k2: finalize softmax scale a_h ----------------------------
__global__ void k2_finalize_a(float* __restrict__ ws, const float* __restrict__ g2) {
    int h = threadIdx.x;
    if (h < 8) {
        const float inv = 1.0f / 33554432.0f;  // N*L*M
        float mean = ws[WS_LIN + h] * inv;
        float var = ws[WS_SSQ + h] * inv - mean * mean;
        ws[WS_A + h] = g2[h] / sqrtf(var + 1e-3f);
    }
}

// ---------------- k3: fused scaled-QK^T -> softmax -> PV --------------------
__global__ __launch_bounds__(256, 1) void k3_attn(const float* __restrict__ query,
                                                  const float* __restrict__ key,
                                                  const float* __restrict__ value,
                                                  float* __restrict__ ws,
                                                  float* __restrict__ out) {
    const int nh = blockIdx.y;
    const int n = nh >> 3, h = nh & 7;
    const int lt = blockIdx.x * 64;
    const int tid = threadIdx.x;

    __shared__ float Ks[64][260];   // K, then reused for V
    __shared__ float Ss[64][260];   // scores -> exp weights
    __shared__ float Qs[64][68];    // Q tile [d][l]
    __shared__ float rowinv[64];

    // stage K [64 d][256 m]
    const float4* kp4 = (const float4*)(key + (size_t)nh * D_B * M_B);
#pragma unroll
    for (int i = 0; i < 16; ++i) {
        int idx4 = i * 256 + tid;
        int d = idx4 >> 6, mf = idx4 & 63;
        *(float4*)&Ks[d][mf * 4] = kp4[idx4];
    }
    // stage Q tile [64 d][64 l]
    const float* qp = query + (size_t)nh * D_B * L_B + lt;
#pragma unroll
    for (int i = 0; i < 4; ++i) {
        int idx4 = i * 256 + tid;
        int d = idx4 >> 4, lf = idx4 & 15;
        *(float4*)&Qs[d][lf * 4] = *(const float4*)&qp[(size_t)d * L_B + lf * 4];
    }
    const float ascale = ws[WS_A + h];
    __syncthreads();

    // Phase A: S[64 l][256 m] = Q^T K, 8x8 register micro-tiles
    const int tr = tid >> 5, tc = tid & 31;   // l-group 0..7, m-group 0..31
    float acc[8][8] = {};
#pragma unroll 4
    for (int d = 0; d < 64; ++d) {
        float4 qa = *(const float4*)&Qs[d][tr * 8];
        float4 qb = *(const float4*)&Qs[d][tr * 8 + 4];
        float2 k0 = *(const float2*)&Ks[d][tc * 2];
        float2 k1 = *(const float2*)&Ks[d][tc * 2 + 64];
        float2 k2 = *(const float2*)&Ks[d][tc * 2 + 128];
        float2 k3 = *(const float2*)&Ks[d][tc * 2 + 192];
        float qv[8] = {qa.x, qa.y, qa.z, qa.w, qb.x, qb.y, qb.z, qb.w};
        float kv[8] = {k0.x, k0.y, k1.x, k1.y, k2.x, k2.y, k3.x, k3.y};
#pragma unroll
        for (int i = 0; i < 8; ++i)
#pragma unroll
            for (int j = 0; j < 8; ++j) acc[i][j] += qv[i] * kv[j];
    }
    __syncthreads();   // everyone done reading Ks (K)

    // issue V loads early (hide HBM/L2 latency under the Ss writes)
    const float4* vp4 = (const float4*)(value + (size_t)nh * C_B * M_B);
    float4 vbuf[16];
#pragma unroll
    for (int i = 0; i < 16; ++i) vbuf[i] = vp4[i * 256 + tid];

    // write scaled scores: m_j = (j>>1)*64 + tc*2 + (j&1)
#pragma unroll
    for (int i = 0; i < 8; ++i) {
        int row = tr * 8 + i;
#pragma unroll
        for (int g = 0; g < 4; ++g) {
            float2 st = {acc[i][g * 2] * ascale, acc[i][g * 2 + 1] * ascale};
            *(float2*)&Ss[row][g * 64 + tc * 2] = st;
        }
    }
    // V into the Ks region
#pragma unroll
    for (int i = 0; i < 16; ++i) {
        int idx4 = i * 256 + tid;
        int d = idx4 >> 6, mf = idx4 & 63;
        *(float4*)&Ks[d][mf * 4] = vbuf[i];
    }
    __syncthreads();

    // Phase B: softmax rows (4 lanes per row, strided m => conflict-free)
    {
        const int r = tid >> 2, qq = tid & 3;
        float sv[64];
        float mx = -1e30f;
#pragma unroll
        for (int k = 0; k < 64; ++k) {
            sv[k] = Ss[r][qq + 4 * k];
            mx = fmaxf(mx, sv[k]);
        }
        mx = fmaxf(mx, __shfl_xor(mx, 1));
        mx = fmaxf(mx, __shfl_xor(mx, 2));
        float sum = 0.f;
#pragma unroll
        for (int k = 0; k < 64; ++k) {
            float e = __expf(sv[k] - mx);
            Ss[r][qq + 4 * k] = e;
            sum += e;
        }
        sum += __shfl_xor(sum, 1);
        sum += __shfl_xor(sum, 2);
        if (qq == 0) rowinv[r] = 1.0f / sum;
    }
    __syncthreads();

    // Phase C: O[c][l] = sum_m E[l][m] * V[c][m]; c = ci*16+tr2, l = li*16+tc2
    const int tr2 = tid >> 4, tc2 = tid & 15;
    float acc2[4][4] = {};   // [ci][li]
    for (int mb = 0; mb < 64; ++mb) {
        const int m4 = mb * 4;
        float4 ev[4], vv[4];
#pragma unroll
        for (int li = 0; li < 4; ++li) ev[li] = *(const float4*)&Ss[li * 16 + tc2][m4];
#pragma unroll
        for (int ci = 0; ci < 4; ++ci) vv[ci] = *(const float4*)&Ks[ci * 16 + tr2][m4];
#pragma unroll
        for (int ci = 0; ci < 4; ++ci)
#pragma unroll
            for (int li = 0; li < 4; ++li)
                acc2[ci][li] += vv[ci].x * ev[li].x + vv[ci].y * ev[li].y +
                                vv[ci].z * ev[li].z + vv[ci].w * ev[li].w;
    }

    // epilogue: normalize by softmax denom, write rv to d_out, BN1d partials
    float* s1 = ws + WS_S1 + h * 64;
    float* s2 = ws + WS_S2 + h * 64;
#pragma unroll
    for (int ci = 0; ci < 4; ++ci) {
        const int c = ci * 16 + tr2;
        float p1 = 0.f, p2 = 0.f;
        float* op = out + ((size_t)(n * HC + h * C_B + c)) * L_B + lt;
#pragma unroll
        for (int li = 0; li < 4; ++li) {
            float val = acc2[ci][li] * rowinv[li * 16 + tc2];
            op[li * 16 + tc2] = val;
            p1 += val;
            p2 += val * val;
        }
#pragma unroll
        for (int off = 1; off < 16; off <<= 1) {
            p1 += __shfl_xor(p1, off);
            p2 += __shfl_xor(p2, off);
        }
        if (tc2 == 0) {
            atomicAdd(&s1[c], p1);
            atomicAdd(&s2[c], p2);
        }
    }
}

// ---------------- k4: finalize BN1d scale/shift -----------------------------
__global__ void k4_finalize_bn1(float* __restrict__ ws, const float* __restrict__ g1,
                                const float* __restrict__ b1) {
    int ch = threadIdx.x + blockIdx.x * blockDim.x;
    if (ch < HC) {
        const float inv = 1.0f / 131072.0f;  // N*L
        float mean = ws[WS_S1 + ch] * inv;
        float var = ws[WS_S2 + ch] * inv - mean * mean;
        float sc = g1[ch] / sqrtf(var + 1e-3f);
        ws[WS_SC + ch] = sc;
        ws[WS_SH + ch] = b1[ch] - mean * sc;
    }
}

// ---------------- k5: in-place BN1d + exact GELU on d_out -------------------
__global__ __launch_bounds__(256) void k5_bn_gelu(float* __restrict__ out,
                                                  const float* __restrict__ ws) {
    const size_t total4 = (size_t)N_B * HC * L_B / 4;  // 16,777,216
    size_t i = (size_t)blockIdx.x * blockDim.x + threadIdx.x;
    const size_t stride = (size_t)gridDim.x * blockDim.x;
    for (; i < total4; i += stride) {
        int ch = (int)((i >> 12) & 511);   // 4096 float4 per (n,ch) row
        float sc = ws[WS_SC + ch], sh = ws[WS_SH + ch];
        float4 v = ((float4*)out)[i];
        float x0 = v.x * sc + sh, x1 = v.y * sc + sh;
        float x2 = v.z * sc + sh, x3 = v.w * sc + sh;
        v.x = 0.5f * x0 * (1.0f + erff(x0 * 0.70710678118654752f));
        v.y = 0.5f * x1 * (1.0f + erff(x1 * 0.70710678118654752f));
        v.z = 0.5f * x2 * (1.0f + erff(x2 * 0.70710678118654752f));
        v.w = 0.5f * x3 * (1.0f + erff(x3 * 0.70710678118654752f));
        ((float4*)out)[i] = v;
    }
}

extern "C" void kernel_launch(void* const* d_in, const int* in_sizes, int n_in,
                              void* d_out, int out_size, void* d_ws, size_t ws_size,
                              hipStream_t stream) {
    const float* query = (const float*)d_in[0];
    const float* key   = (const float*)d_in[1];
    const float* value = (const float*)d_in[2];
    const float* g2    = (const float*)d_in[3];
    // d_in[4] = bn2d_beta: provably cancels inside the softmax (constant per row)
    const float* g1    = (const float*)d_in[5];
    const float* b1    = (const float*)d_in[6];
    float* out = (float*)d_out;
    float* ws  = (float*)d_ws;

    hipMemsetAsync(ws, 0, WS_TOT * sizeof(float), stream);
    hipLaunchKernelGGL(k1a_gram_k, dim3(64), dim3(256), 0, stream, key, ws);
    hipLaunchKernelGGL(k1b_stats_q, dim3(64, 64), dim3(256), 0, stream, query, ws);
    hipLaunchKernelGGL(k2_finalize_a, dim3(1), dim3(64), 0, stream, ws, g2);
    hipLaunchKernelGGL(k3_attn, dim3(256, 64), dim3(256), 0, stream, query, key, value, ws, out);
    hipLaunchKernelGGL(k4_finalize_bn1, dim3(2), dim3(256), 0, stream, ws, g1, b1);
    hipLaunchKernelGGL(k5_bn_gelu, dim3(2048), dim3(256), 0, stream, out, ws);
}